// Round 2
// baseline (76235.248 us; speedup 1.0000x reference)
//
#include <hip/hip_runtime.h>
#include <hip/hip_cooperative_groups.h>

namespace cg = cooperative_groups;

#define Tn   512
#define Bn   128
#define Hn   256
#define Jn   1024
#define Fn   256    // G*FIN
#define NBLK 256
#define NTHR 512
#define MARG_BLKS 128

__device__ __forceinline__ float sigmoidf_(float v) {
    return 1.0f / (1.0f + __expf(-v));
}
__device__ __forceinline__ float tanhf_(float v) {
    float ax = fabsf(v);
    float e  = __expf(-2.0f * ax);
    float t  = (1.0f - e) / (1.0f + e);
    return copysignf(t, v);
}

// Workspace layout (floats):
//  hmT: 2 x [G][H][B]  (transposed h_m, double buffered)   = 2*131072
//  hjT: 2 x [J][B]     (transposed h_j, double buffered)   = 2*131072
//  ngT: 2 x [GH][B]    (transposed newgates, double buff)  = 2*131072
// state(t) lives in buf[t&1]; t=-1 (zeros) lives in buf 1.

// ---------------- marginal GRU cell, one step, one block (wg in [0,128)) ----
__device__ __forceinline__ void marg_step(
    int s, int wg, int tid, float* smem,
    const float* __restrict__ x, const float* __restrict__ w_ih,
    const float* __restrict__ w_hh, const float* __restrict__ b_ih,
    float* __restrict__ hmT, float* __restrict__ ngT)
{
    const int lane = tid & 63;
    const int wv   = tid >> 6;          // 0..7
    const int bh   = wg & 1, b0 = bh * 64;
    const int rg   = wg >> 1;           // 0..63  (16 global rows each)
    const int R    = rg * 16 + wv * 2;  // global (g,h) row, this wave: R, R+1
    const int g    = R >> 8;
    const int hA   = R & 255;           // row within group

    float* S_x = smem;                  // [64 f][64 b] swizzled
    float* S_h = smem + 4096;           // [64 k][64 b]

    const float* wih_g = w_ih + (size_t)g * 768 * 64;
    const float* whh_g = w_hh + (size_t)g * 768 * 256;

    const float biasr0 = b_ih[g*768 + hA];
    const float biasz0 = b_ih[g*768 + 256 + hA];
    const float biasn0 = b_ih[g*768 + 512 + hA];
    const float biasr1 = b_ih[g*768 + hA + 1];
    const float biasz1 = b_ih[g*768 + 256 + hA + 1];
    const float biasn1 = b_ih[g*768 + 512 + hA + 1];

    const float* hm_old = hmT + ((s+1)&1) * 131072 + g * 32768;
    float*       hm_new = hmT + (s&1)     * 131072 + g * 32768;
    float*       ng_cur = ngT + (s&1)     * 131072;

    float accr0=0.f, accz0=0.f, accin0=0.f, acchn0=0.f;
    float accr1=0.f, accz1=0.f, accin1=0.f, acchn1=0.f;

    // ---- stage x slice [64 f][64 b] transposed+swizzled ----
    __syncthreads();
    for (int i = tid; i < 4096; i += NTHR) {
        int fl = i & 63, bl = i >> 6;
        S_x[fl*64 + ((bl + fl) & 63)] =
            x[((size_t)s*Bn + b0 + bl)*Fn + g*64 + fl];
    }
    __syncthreads();

    // ---- x-part dots (K=64) ----
    {
        const float4* w0r = (const float4*)(wih_g + (size_t)(hA      )*64);
        const float4* w0z = (const float4*)(wih_g + (size_t)(hA + 256)*64);
        const float4* w0n = (const float4*)(wih_g + (size_t)(hA + 512)*64);
        const float4* w1r = (const float4*)(wih_g + (size_t)(hA + 1      )*64);
        const float4* w1z = (const float4*)(wih_g + (size_t)(hA + 1 + 256)*64);
        const float4* w1n = (const float4*)(wih_g + (size_t)(hA + 1 + 512)*64);
        #pragma unroll 4
        for (int k4 = 0; k4 < 16; ++k4) {
            int k = k4 * 4;
            float x0 = S_x[(k+0)*64 + ((lane + k+0) & 63)];
            float x1 = S_x[(k+1)*64 + ((lane + k+1) & 63)];
            float x2 = S_x[(k+2)*64 + ((lane + k+2) & 63)];
            float x3 = S_x[(k+3)*64 + ((lane + k+3) & 63)];
            float4 a;
            a = w0r[k4]; accr0  += a.x*x0 + a.y*x1 + a.z*x2 + a.w*x3;
            a = w0z[k4]; accz0  += a.x*x0 + a.y*x1 + a.z*x2 + a.w*x3;
            a = w0n[k4]; accin0 += a.x*x0 + a.y*x1 + a.z*x2 + a.w*x3;
            a = w1r[k4]; accr1  += a.x*x0 + a.y*x1 + a.z*x2 + a.w*x3;
            a = w1z[k4]; accz1  += a.x*x0 + a.y*x1 + a.z*x2 + a.w*x3;
            a = w1n[k4]; accin1 += a.x*x0 + a.y*x1 + a.z*x2 + a.w*x3;
        }
    }

    // ---- h-part dots (K=256, 4 chunks of 64) ----
    for (int kc = 0; kc < 4; ++kc) {
        __syncthreads();
        for (int i = tid; i < 4096; i += NTHR) {
            int bl = i & 63, kl = i >> 6;
            S_h[kl*64 + bl] = hm_old[(kc*64 + kl)*128 + b0 + bl];
        }
        __syncthreads();
        const float4* w0r = (const float4*)(whh_g + (size_t)(hA      )*256 + kc*64);
        const float4* w0z = (const float4*)(whh_g + (size_t)(hA + 256)*256 + kc*64);
        const float4* w0n = (const float4*)(whh_g + (size_t)(hA + 512)*256 + kc*64);
        const float4* w1r = (const float4*)(whh_g + (size_t)(hA + 1      )*256 + kc*64);
        const float4* w1z = (const float4*)(whh_g + (size_t)(hA + 1 + 256)*256 + kc*64);
        const float4* w1n = (const float4*)(whh_g + (size_t)(hA + 1 + 512)*256 + kc*64);
        #pragma unroll 4
        for (int k4 = 0; k4 < 16; ++k4) {
            int k = k4 * 4;
            float h0v = S_h[(k+0)*64 + lane];
            float h1v = S_h[(k+1)*64 + lane];
            float h2v = S_h[(k+2)*64 + lane];
            float h3v = S_h[(k+3)*64 + lane];
            float4 a;
            a = w0r[k4]; accr0  += a.x*h0v + a.y*h1v + a.z*h2v + a.w*h3v;
            a = w0z[k4]; accz0  += a.x*h0v + a.y*h1v + a.z*h2v + a.w*h3v;
            a = w0n[k4]; acchn0 += a.x*h0v + a.y*h1v + a.z*h2v + a.w*h3v;
            a = w1r[k4]; accr1  += a.x*h0v + a.y*h1v + a.z*h2v + a.w*h3v;
            a = w1z[k4]; accz1  += a.x*h0v + a.y*h1v + a.z*h2v + a.w*h3v;
            a = w1n[k4]; acchn1 += a.x*h0v + a.y*h1v + a.z*h2v + a.w*h3v;
        }
    }

    // ---- gates + state update ----
    {
        float r = sigmoidf_(accr0 + biasr0);
        float z = sigmoidf_(accz0 + biasz0);
        float n = tanhf_(accin0 + biasn0 + r * acchn0);
        float hmo = hm_old[hA*128 + b0 + lane];
        hm_new[hA*128 + b0 + lane] = n + z * (hmo - n);
        ng_cur[(g*256 + hA)*128 + b0 + lane] = n;
    }
    {
        float r = sigmoidf_(accr1 + biasr1);
        float z = sigmoidf_(accz1 + biasz1);
        float n = tanhf_(accin1 + biasn1 + r * acchn1);
        float hmo = hm_old[(hA+1)*128 + b0 + lane];
        hm_new[(hA+1)*128 + b0 + lane] = n + z * (hmo - n);
        ng_cur[(g*256 + hA + 1)*128 + b0 + lane] = n;
    }
}

// ---------------- joint cell, one step u, one block (wg2 in [0,128)) -------
__device__ __forceinline__ void joint_step(
    int u, int wg2, int tid, float* smem,
    const float* __restrict__ x, const float* __restrict__ u_c,
    const float* __restrict__ b_c, const float* __restrict__ w_z,
    const float* __restrict__ u_z, const float* __restrict__ b_z,
    float* __restrict__ hjT, const float* __restrict__ ngT,
    float* __restrict__ out)
{
    const int lane = tid & 63;
    const int wv   = tid >> 6;
    const int bh   = wg2 & 1, b0 = bh * 64;
    const int jg   = wg2 >> 1;            // 0..63, 16 j rows each
    const int jA   = jg * 16 + wv * 2;

    float* S_a = smem;                    // [64 k][64 b]
    float* S_b = smem + 4096;

    const float* ucA = u_c + (size_t)jA * 1024;
    const float* ucB = u_c + (size_t)(jA+1) * 1024;
    const float* uzA = u_z + (size_t)jA * 1024;
    const float* uzB = u_z + (size_t)(jA+1) * 1024;
    const float bcA = b_c[jA], bcB = b_c[jA+1];
    const float bzA = b_z[jA], bzB = b_z[jA+1];

    const float* ng_u   = ngT + (u&1)     * 131072;
    const float* hj_old = hjT + ((u+1)&1) * 131072;
    float*       hj_new = hjT + (u&1)     * 131072;

    float accc0=0.f, accc1=0.f, accz0=0.f, accz1=0.f;

    // ---- K=1024 over ng (c) and h_j (z), chunks of 64 ----
    for (int kc = 0; kc < 16; ++kc) {
        __syncthreads();
        for (int i = tid; i < 4096; i += NTHR) {
            int bl = i & 63, kl = i >> 6;
            S_a[kl*64 + bl] = ng_u  [(kc*64 + kl)*128 + b0 + bl];
            S_b[kl*64 + bl] = hj_old[(kc*64 + kl)*128 + b0 + bl];
        }
        __syncthreads();
        const float4* pcA = (const float4*)(ucA + kc*64);
        const float4* pcB = (const float4*)(ucB + kc*64);
        const float4* pzA = (const float4*)(uzA + kc*64);
        const float4* pzB = (const float4*)(uzB + kc*64);
        #pragma unroll 4
        for (int k4 = 0; k4 < 16; ++k4) {
            int k = k4 * 4;
            float a0 = S_a[(k+0)*64 + lane];
            float a1 = S_a[(k+1)*64 + lane];
            float a2 = S_a[(k+2)*64 + lane];
            float a3 = S_a[(k+3)*64 + lane];
            float h0 = S_b[(k+0)*64 + lane];
            float h1 = S_b[(k+1)*64 + lane];
            float h2 = S_b[(k+2)*64 + lane];
            float h3 = S_b[(k+3)*64 + lane];
            float4 w;
            w = pcA[k4]; accc0 += w.x*a0 + w.y*a1 + w.z*a2 + w.w*a3;
            w = pcB[k4]; accc1 += w.x*a0 + w.y*a1 + w.z*a2 + w.w*a3;
            w = pzA[k4]; accz0 += w.x*h0 + w.y*h1 + w.z*h2 + w.w*h3;
            w = pzB[k4]; accz1 += w.x*h0 + w.y*h1 + w.z*h2 + w.w*h3;
        }
    }

    // ---- x-part of zj (K=256, 4 chunks, transposed+swizzled) ----
    for (int fc = 0; fc < 4; ++fc) {
        __syncthreads();
        for (int i = tid; i < 4096; i += NTHR) {
            int fl = i & 63, bl = i >> 6;
            S_a[fl*64 + ((bl + fl) & 63)] =
                x[((size_t)u*Bn + b0 + bl)*Fn + fc*64 + fl];
        }
        __syncthreads();
        const float4* pxA = (const float4*)(w_z + (size_t)jA*256 + fc*64);
        const float4* pxB = (const float4*)(w_z + (size_t)(jA+1)*256 + fc*64);
        #pragma unroll 4
        for (int k4 = 0; k4 < 16; ++k4) {
            int k = k4 * 4;
            float x0 = S_a[(k+0)*64 + ((lane + k+0) & 63)];
            float x1 = S_a[(k+1)*64 + ((lane + k+1) & 63)];
            float x2 = S_a[(k+2)*64 + ((lane + k+2) & 63)];
            float x3 = S_a[(k+3)*64 + ((lane + k+3) & 63)];
            float4 w;
            w = pxA[k4]; accz0 += w.x*x0 + w.y*x1 + w.z*x2 + w.w*x3;
            w = pxB[k4]; accz1 += w.x*x0 + w.y*x1 + w.z*x2 + w.w*x3;
        }
    }

    // ---- joint gate + state update ----
    {
        float c  = tanhf_(accc0 + bcA);
        float zj = sigmoidf_(accz0 + bzA);
        float hjo = hj_old[jA*128 + b0 + lane];
        float hn = c + zj * (hjo - c);
        hj_new[jA*128 + b0 + lane] = hn;
        if (u == Tn-1) out[(size_t)(b0 + lane)*Jn + jA] = hn;
    }
    {
        float c  = tanhf_(accc1 + bcB);
        float zj = sigmoidf_(accz1 + bzB);
        float hjo = hj_old[(jA+1)*128 + b0 + lane];
        float hn = c + zj * (hjo - c);
        hj_new[(jA+1)*128 + b0 + lane] = hn;
        if (u == Tn-1) out[(size_t)(b0 + lane)*Jn + jA + 1] = hn;
    }
}

// ---------------- persistent cooperative kernel ---------------------------
__launch_bounds__(NTHR, 2)
__global__ void mgrn_coop(const float* __restrict__ x,
                          const float* __restrict__ w_ih,
                          const float* __restrict__ w_hh,
                          const float* __restrict__ b_ih,
                          const float* __restrict__ u_c,
                          const float* __restrict__ b_c,
                          const float* __restrict__ w_z,
                          const float* __restrict__ u_z,
                          const float* __restrict__ b_z,
                          float* __restrict__ out,
                          float* __restrict__ ws)
{
    cg::grid_group grid = cg::this_grid();
    __shared__ float smem[8192];   // 32 KiB

    float* hmT = ws;               // 2*131072
    float* hjT = ws + 262144;
    float* ngT = ws + 524288;

    const int tid = threadIdx.x;
    const int wg  = blockIdx.x;

    // zero the t=-1 buffers (buf 1) of hmT and hjT
    {
        int gidx = wg * NTHR + tid;          // 0..131071
        hmT[131072 + gidx] = 0.0f;
        hjT[131072 + gidx] = 0.0f;
    }
    grid.sync();

    for (int s = 0; s <= Tn; ++s) {
        if (wg < MARG_BLKS) {
            if (s < Tn)
                marg_step(s, wg, tid, smem, x, w_ih, w_hh, b_ih, hmT, ngT);
        } else {
            if (s >= 1)
                joint_step(s-1, wg - MARG_BLKS, tid, smem, x, u_c, b_c,
                           w_z, u_z, b_z, hjT, ngT, out);
        }
        grid.sync();
    }
}

// ---------------- fallback: one step per launch ---------------------------
__launch_bounds__(NTHR, 2)
__global__ void mgrn_step(const float* __restrict__ x,
                          const float* __restrict__ w_ih,
                          const float* __restrict__ w_hh,
                          const float* __restrict__ b_ih,
                          const float* __restrict__ u_c,
                          const float* __restrict__ b_c,
                          const float* __restrict__ w_z,
                          const float* __restrict__ u_z,
                          const float* __restrict__ b_z,
                          float* __restrict__ out,
                          float* __restrict__ ws,
                          int s)
{
    __shared__ float smem[8192];
    float* hmT = ws;
    float* hjT = ws + 262144;
    float* ngT = ws + 524288;
    const int tid = threadIdx.x;
    const int wg  = blockIdx.x;

    if (wg < MARG_BLKS) {
        if (s < Tn)
            marg_step(s, wg, tid, smem, x, w_ih, w_hh, b_ih, hmT, ngT);
    } else {
        if (s >= 1)
            joint_step(s-1, wg - MARG_BLKS, tid, smem, x, u_c, b_c,
                       w_z, u_z, b_z, hjT, ngT, out);
    }
}

extern "C" void kernel_launch(void* const* d_in, const int* in_sizes, int n_in,
                              void* d_out, int out_size, void* d_ws, size_t ws_size,
                              hipStream_t stream) {
    const float* x    = (const float*)d_in[0];
    const float* w_ih = (const float*)d_in[1];
    const float* w_hh = (const float*)d_in[2];
    const float* b_ih = (const float*)d_in[3];
    const float* u_c  = (const float*)d_in[4];
    const float* b_c  = (const float*)d_in[5];
    const float* w_z  = (const float*)d_in[6];
    const float* u_z  = (const float*)d_in[7];
    const float* b_z  = (const float*)d_in[8];
    float* out = (float*)d_out;
    float* ws  = (float*)d_ws;

    void* args[] = {&x, &w_ih, &w_hh, &b_ih, &u_c, &b_c, &w_z, &u_z, &b_z, &out, &ws};
    hipError_t e = hipLaunchCooperativeKernel((void*)mgrn_coop, dim3(NBLK), dim3(NTHR),
                                              args, 0, stream);
    if (e != hipSuccess) {
        (void)hipGetLastError();   // clear sticky error
        hipMemsetAsync(ws, 0, (size_t)786432 * sizeof(float), stream);
        for (int s = 0; s <= Tn; ++s) {
            mgrn_step<<<dim3(NBLK), dim3(NTHR), 0, stream>>>(
                x, w_ih, w_hh, b_ih, u_c, b_c, w_z, u_z, b_z, out, ws, s);
        }
    }
}